// Round 17
// baseline (198.129 us; speedup 1.0000x reference)
//
#include <hip/hip_runtime.h>

// GCN: 2x GCNConv (5->16->32) + global mean pool + linear head.
// v16: v15 build pipeline (count->scan->LDS-staged scatter->LDS counting sort
// with fused dinv/sx8 prep) + float4-vectorized deep-batch gathers with
// zero-row tail masking, and both linear layers fused into the gather
// epilogues (k_lin1 -> gather8, k_fin -> gather16). agg8/agg16 buffers and
// 2 kernels deleted. Tables get a zeroed row at index N for masked slots.

#define RANGE 256          // nodes per bucket (d>>8)
#define NB 391             // ceil(100000/256)
#define RPB (RANGE + 1)    // rowp entries per bucket (incl. end)
#define CAP 10240          // record capacity per bucket (exact fill ~8184+-90)
#define NBLK 512           // edge-pass blocks
#define CHUNKMAX 6400      // >= ceil(E/NBLK) = 6250
#define PSPREAD 8

// per-block LDS histogram of dst buckets -> blkcnt[blk][NB] (coalesced row)
__global__ void k_cnt(const int* __restrict__ dst, int E, int chunk,
                      int* __restrict__ blkcnt) {
    __shared__ int h[NB];
    for (int t = threadIdx.x; t < NB; t += blockDim.x) h[t] = 0;
    __syncthreads();
    int e0 = blockIdx.x * chunk;
    int e1 = min(e0 + chunk, E);
    for (int e = e0 + threadIdx.x; e < e1; e += blockDim.x)
        atomicAdd(&h[dst[e] >> 8], 1);
    __syncthreads();
    int* row = blkcnt + (size_t)blockIdx.x * NB;
    for (int t = threadIdx.x; t < NB; t += blockDim.x) row[t] = h[t];
}

// one block per bucket: exclusive scan over the NBLK per-block counts.
__global__ __launch_bounds__(512) void k_scanb(const int* __restrict__ blkcnt,
        int* __restrict__ base, int* __restrict__ bfill) {
    __shared__ int part[NBLK];
    int b = blockIdx.x, t = threadIdx.x;   // NBLK == 512 threads
    int v = blkcnt[(size_t)t * NB + b];    // column read, L2-cached
    part[t] = v;
    __syncthreads();
    for (int off = 1; off < NBLK; off <<= 1) {
        int u = (t >= off) ? part[t - off] : 0;
        __syncthreads();
        part[t] += u;
        __syncthreads();
    }
    base[(size_t)b * NBLK + t] = b * CAP + part[t] - v;  // coalesced row write
    if (t == NBLK - 1) bfill[b] = part[t];
}

// scatter records at exact offsets, via LDS staging sorted by bucket, then
// burst writes (consecutive lanes -> consecutive addresses per segment).
__global__ __launch_bounds__(512) void k_scat(const int* __restrict__ src,
        const int* __restrict__ dst, int E, int chunk,
        const int* __restrict__ base, unsigned int* __restrict__ recbuf) {
    __shared__ unsigned int lbuf[CHUNKMAX];
    __shared__ unsigned short bkt[CHUNKMAX];
    __shared__ int h[NB], lsc[NB], h2[NB], base_l[NB];
    __shared__ int sc[512];
    int t = threadIdx.x;
    if (t < NB) { h[t] = 0; h2[t] = 0; }
    __syncthreads();
    int e0 = blockIdx.x * chunk;
    int e1 = min(e0 + chunk, E);
    int len = e1 - e0;
    for (int e = e0 + t; e < e1; e += 512)
        atomicAdd(&h[__builtin_nontemporal_load(dst + e) >> 8], 1);
    __syncthreads();
    int v = (t < NB) ? h[t] : 0;
    sc[t] = v;
    __syncthreads();
    for (int off = 1; off < 512; off <<= 1) {
        int u = (t >= off) ? sc[t - off] : 0;
        __syncthreads();
        sc[t] += u;
        __syncthreads();
    }
    if (t < NB) {
        lsc[t] = sc[t] - v;
        base_l[t] = base[(size_t)t * NBLK + blockIdx.x];  // column read, L2-cached
    }
    __syncthreads();
    for (int e = e0 + t; e < e1; e += 512) {
        int d = __builtin_nontemporal_load(dst + e);
        int s = __builtin_nontemporal_load(src + e);
        int b = d >> 8;
        int r = atomicAdd(&h2[b], 1);
        int pos = lsc[b] + r;
        lbuf[pos] = ((unsigned)s << 8) | (unsigned)(d & 255);
        bkt[pos] = (unsigned short)b;
    }
    __syncthreads();
    for (int i = t; i < len; i += 512) {
        int b = bkt[i];
        recbuf[base_l[b] + (i - lsc[b])] = lbuf[i];  // burst per segment
    }
}

// per-bucket LDS counting sort by dst_local; cnt[] doubles as degree, so
// dinv and sx8 (= [dinv*x, 0,0,0]) are computed here too (fused prep).
__global__ __launch_bounds__(512) void k_sort(const int* __restrict__ bfill,
        const unsigned int* __restrict__ recbuf, int* __restrict__ rowp,
        int* __restrict__ srt, const float* __restrict__ x,
        float* __restrict__ dinv, float* __restrict__ sx8, int N) {
    __shared__ int cnt[RANGE], lbase[RANGE], rank[RANGE], sc[RANGE];
    int b = blockIdx.x;
    int t = threadIdx.x;
    if (t < RANGE) { cnt[t] = 0; rank[t] = 0; }
    __syncthreads();
    int len = bfill[b];
    int g0 = b * CAP;
    const unsigned* rb = recbuf + (size_t)g0;
    for (int r = t; r < len; r += 512)
        atomicAdd(&cnt[__builtin_nontemporal_load(rb + r) & 255], 1);
    __syncthreads();
    if (t < RANGE) sc[t] = cnt[t];
    __syncthreads();
    for (int off = 1; off < RANGE; off <<= 1) {
        int u = 0;
        if (t < RANGE && t >= off) u = sc[t - off];
        __syncthreads();
        if (t < RANGE) sc[t] += u;
        __syncthreads();
    }
    if (t < RANGE) {
        lbase[t] = sc[t] - cnt[t];
        rowp[b * RPB + t] = g0 + lbase[t];
        if (t == RANGE - 1) rowp[b * RPB + RANGE] = g0 + sc[t];
        int i = b * RANGE + t;
        if (i < N) {
            float di = rsqrtf((float)(cnt[t] + 1));
            dinv[i] = di;
            float4 a, bb;
            a.x = x[i * 5 + 0] * di; a.y = x[i * 5 + 1] * di;
            a.z = x[i * 5 + 2] * di; a.w = x[i * 5 + 3] * di;
            bb.x = x[i * 5 + 4] * di; bb.y = 0.f; bb.z = 0.f; bb.w = 0.f;
            float4* p = (float4*)(sx8 + (size_t)i * 8);
            p[0] = a; p[1] = bb;
        }
    }
    __syncthreads();
    for (int r = t; r < len; r += 512) {
        unsigned rec = __builtin_nontemporal_load(rb + r);
        int key = (int)(rec & 255);
        int pos = g0 + lbase[key] + atomicAdd(&rank[key], 1);
        srt[pos] = (int)(rec >> 8);   // plain store: L2-merged in bucket slice
    }
}

// one wave per node (+1 zero-row wave); 2 feature-lanes x float4 x 32 slot
// groups x depth 2 (64 edges per latency round). Masked slots clamp to the
// zeroed row N. Epilogue: fused 5->16 linear -> writes g directly.
__global__ void k_gather8(const int* __restrict__ rowp, const int* __restrict__ srt,
                          const float* __restrict__ sx8, const float* __restrict__ W1,
                          const float* __restrict__ b1, const float* __restrict__ dinv,
                          float* __restrict__ g, int N) {
    __shared__ float sW[80], sb[16];
    if (threadIdx.x < 80) sW[threadIdx.x] = W1[threadIdx.x];
    if (threadIdx.x < 16) sb[threadIdx.x] = b1[threadIdx.x];
    __syncthreads();
    int wid = (blockIdx.x * blockDim.x + threadIdx.x) >> 6;
    int lane = threadIdx.x & 63;
    if (wid > N) return;
    if (wid == N) {               // write the zero row of g (for gather16 tails)
        if (lane < 16) g[(size_t)N * 16 + lane] = 0.f;
        return;
    }
    int k2 = lane & 1, j = lane >> 1;
    int b = wid >> 8, dl = wid & 255;
    int base = b * RPB + dl;
    int p0 = rowp[base], p1 = rowp[base + 1];
    const float4* tab = (const float4*)sx8;
    float ax = 0.f, ay = 0.f, az = 0.f, aw = 0.f;
    int p = p0 + j;
    while (p < p1) {
        int s0 = __builtin_nontemporal_load(srt + p);
        int s1 = __builtin_nontemporal_load(srt + p + 32);
        s1 = (p + 32 < p1) ? s1 : N;
        float4 v0 = tab[(size_t)s0 * 2 + k2];
        float4 v1 = tab[(size_t)s1 * 2 + k2];
        ax += v0.x + v1.x; ay += v0.y + v1.y;
        az += v0.z + v1.z; aw += v0.w + v1.w;
        p += 64;
    }
#pragma unroll
    for (int off = 2; off <= 32; off <<= 1) {
        ax += __shfl_xor(ax, off, 64);
        ay += __shfl_xor(ay, off, 64);
        az += __shfl_xor(az, off, 64);
        aw += __shfl_xor(aw, off, 64);
    }
    float4 self = tab[(size_t)wid * 2 + k2];    // self-loop
    ax += self.x; ay += self.y; az += self.z; aw += self.w;
    // broadcast the 5 aggregated features (lane0 holds f0-3, lane1 holds f4-7)
    float a0 = __shfl(ax, 0, 64);
    float a1 = __shfl(ay, 0, 64);
    float a2 = __shfl(az, 0, 64);
    float a3 = __shfl(aw, 0, 64);
    float a4 = __shfl(ax, 1, 64);
    if (lane < 16) {
        float di = dinv[wid];
        float h = a0 * sW[0 * 16 + lane];
        h = fmaf(a1, sW[1 * 16 + lane], h);
        h = fmaf(a2, sW[2 * 16 + lane], h);
        h = fmaf(a3, sW[3 * 16 + lane], h);
        h = fmaf(a4, sW[4 * 16 + lane], h);
        h = fmaxf(fmaf(di, h, sb[lane]), 0.f);
        g[(size_t)wid * 16 + lane] = h * di;
    }
}

// one wave per node; 4 feature-lanes x float4 x 16 slot groups x depth 4
// (64 edges per latency round; a lane-quad covers a 64B g-row exactly).
// Epilogue: fused 16->32 linear + relu + fcW dot + pool atomic (was k_fin).
__global__ void k_gather16(const int* __restrict__ rowp, const int* __restrict__ srt,
                           const float* __restrict__ g, const float* __restrict__ W2,
                           const float* __restrict__ b2, const float* __restrict__ fcW,
                           const float* __restrict__ dinv, const int* __restrict__ batch,
                           float* __restrict__ pool, int* __restrict__ gcnt,
                           int N, int G) {
    __shared__ float sW[512], sb[32], sf[32];
    for (int t = threadIdx.x; t < 512; t += blockDim.x) sW[t] = W2[t];
    if (threadIdx.x < 32) {
        sb[threadIdx.x] = b2[threadIdx.x];
        sf[threadIdx.x] = fcW[threadIdx.x];
    }
    __syncthreads();
    int wid = (blockIdx.x * blockDim.x + threadIdx.x) >> 6;
    int lane = threadIdx.x & 63;
    if (wid >= N) return;
    int k4 = lane & 3, j = lane >> 2;
    int b = wid >> 8, dl = wid & 255;
    int base = b * RPB + dl;
    int p0 = rowp[base], p1 = rowp[base + 1];
    const float4* tab = (const float4*)g;
    float ax = 0.f, ay = 0.f, az = 0.f, aw = 0.f;
    int p = p0 + j;
    while (p < p1) {
        int s0 = __builtin_nontemporal_load(srt + p);
        int s1 = __builtin_nontemporal_load(srt + p + 16);
        int s2 = __builtin_nontemporal_load(srt + p + 32);
        int s3 = __builtin_nontemporal_load(srt + p + 48);
        s1 = (p + 16 < p1) ? s1 : N;
        s2 = (p + 32 < p1) ? s2 : N;
        s3 = (p + 48 < p1) ? s3 : N;
        float4 v0 = tab[(size_t)s0 * 4 + k4];
        float4 v1 = tab[(size_t)s1 * 4 + k4];
        float4 v2 = tab[(size_t)s2 * 4 + k4];
        float4 v3 = tab[(size_t)s3 * 4 + k4];
        ax += (v0.x + v1.x) + (v2.x + v3.x);
        ay += (v0.y + v1.y) + (v2.y + v3.y);
        az += (v0.z + v1.z) + (v2.z + v3.z);
        aw += (v0.w + v1.w) + (v2.w + v3.w);
        p += 64;
    }
#pragma unroll
    for (int off = 4; off <= 32; off <<= 1) {
        ax += __shfl_xor(ax, off, 64);
        ay += __shfl_xor(ay, off, 64);
        az += __shfl_xor(az, off, 64);
        aw += __shfl_xor(aw, off, 64);
    }
    float4 self = tab[(size_t)wid * 4 + k4];    // self-loop
    ax += self.x; ay += self.y; az += self.z; aw += self.w;
    // broadcast all 16 aggregated features (lane q in 0..3 holds f[4q..4q+3])
    float a[16];
#pragma unroll
    for (int q = 0; q < 4; ++q) {
        a[4 * q + 0] = __shfl(ax, q, 64);
        a[4 * q + 1] = __shfl(ay, q, 64);
        a[4 * q + 2] = __shfl(az, q, 64);
        a[4 * q + 3] = __shfl(aw, q, 64);
    }
    float di = dinv[wid];
    int jj = lane & 31;
    float h = 0.f;
#pragma unroll
    for (int kk = 0; kk < 16; ++kk) h = fmaf(a[kk], sW[kk * 32 + jj], h);
    h = fmaxf(fmaf(di, h, sb[jj]), 0.f);
    float c = (lane < 32) ? h * sf[jj] : 0.f;
#pragma unroll
    for (int off = 1; off <= 32; off <<= 1) c += __shfl_xor(c, off, 64);
    if (lane == 0) {
        int bidx = batch[wid];
        int slot = wid & (PSPREAD - 1);
        atomicAdd(&pool[slot * G + bidx], c);
        atomicAdd(&gcnt[slot * G + bidx], 1);
    }
}

__global__ void k_out(const float* __restrict__ pool, const int* __restrict__ gcnt,
                      const float* __restrict__ fcb, float* __restrict__ out, int G) {
    int gI = blockIdx.x * blockDim.x + threadIdx.x;
    if (gI >= G) return;
    float s = 0.f; int c = 0;
#pragma unroll
    for (int k = 0; k < PSPREAD; ++k) { s += pool[k * G + gI]; c += gcnt[k * G + gI]; }
    out[gI] = s / fmaxf((float)c, 1.f) + fcb[0];
}

extern "C" void kernel_launch(void* const* d_in, const int* in_sizes, int n_in,
                              void* d_out, int out_size, void* d_ws, size_t ws_size,
                              hipStream_t stream) {
    const float* x    = (const float*)d_in[0];
    const int*   ei   = (const int*)d_in[1];
    const int*   batch= (const int*)d_in[2];
    const float* W1   = (const float*)d_in[3];
    const float* b1   = (const float*)d_in[4];
    const float* W2   = (const float*)d_in[5];
    const float* b2   = (const float*)d_in[6];
    const float* fcW  = (const float*)d_in[7];
    const float* fcb  = (const float*)d_in[8];
    float* out = (float*)d_out;

    const int N = in_sizes[0] / 5;
    const int E = in_sizes[1] / 2;
    const int G = out_size;  // 1024
    const int chunk = (E + NBLK - 1) / NBLK;  // 6250 <= CHUNKMAX

    const int* src = ei;
    const int* dst = ei + E;

    // workspace carve, every buffer 256B-aligned
    char* ws = (char*)d_ws;
    size_t o = 0;
    auto carve = [&](size_t bytes) -> char* {
        char* p = ws + o;
        o += (bytes + 255) & ~(size_t)255;
        return p;
    };
    int*   bfill   = (int*)carve((size_t)4 * NB);
    int*   rowp    = (int*)carve((size_t)4 * (NB * RPB + 4));
    float* dinv    = (float*)carve((size_t)4 * N);
    float* sx8     = (float*)carve((size_t)32 * (N + 1));        // +1 zero row
    int*   srt     = (int*)carve((size_t)4 * NB * CAP + 256);    // 16 MB + pad
    char*  rbase   = carve((size_t)4 * NB * CAP);                // 16 MB
    // blkcnt/base alias srt (dead before k_sort writes srt)
    int*   blkcnt  = srt;                                        // [NBLK][NB]
    int*   base    = srt + (size_t)NBLK * NB;                    // [NB][NBLK]
    unsigned int* recbuf = (unsigned int*)rbase;                 // dead after k_sort
    float* g       = (float*)rbase;                              // (N+1)x16 floats, written post-k_sort
    float* pool    = (float*)carve((size_t)4 * PSPREAD * G);
    int*   gcnt    = (int*)carve((size_t)4 * PSPREAD * G);

    hipMemsetAsync(pool, 0, (size_t)4 * PSPREAD * G, stream);
    hipMemsetAsync(gcnt, 0, (size_t)4 * PSPREAD * G, stream);
    hipMemsetAsync(sx8 + (size_t)8 * N, 0, 32, stream);          // zero row N

    k_cnt<<<NBLK, 256, 0, stream>>>(dst, E, chunk, blkcnt);
    k_scanb<<<NB, 512, 0, stream>>>(blkcnt, base, bfill);
    k_scat<<<NBLK, 512, 0, stream>>>(src, dst, E, chunk, base, recbuf);
    k_sort<<<NB, 512, 0, stream>>>(bfill, recbuf, rowp, srt, x, dinv, sx8, N);
    {
        long long T = (long long)(N + 1) * 64;
        k_gather8<<<(int)((T + 255) / 256), 256, 0, stream>>>(rowp, srt, sx8, W1, b1, dinv, g, N);
    }
    {
        long long T = (long long)N * 64;
        k_gather16<<<(int)((T + 255) / 256), 256, 0, stream>>>(rowp, srt, g, W2, b2, fcW,
                                                              dinv, batch, pool, gcnt, N, G);
    }
    k_out<<<(G + 255) / 256, 256, 0, stream>>>(pool, gcnt, fcb, out, G);
}